// Round 3
// baseline (541.525 us; speedup 1.0000x reference)
//
#include <hip/hip_runtime.h>
#include <math.h>

// ---------------- CSR build (single-atomic counting sort) ----------------

__global__ __launch_bounds__(256) void rank_k(const int* __restrict__ dst, int* cnt,
                                              int* __restrict__ rank, int E) {
    int e = blockIdx.x * 256 + threadIdx.x;
    if (e < E) {
        int d = dst[e];
        rank[e] = atomicAdd(&cnt[d], 1);
    }
}

__global__ __launch_bounds__(256) void scan1_k(const int* __restrict__ cnt, int* bsum, int n) {
    __shared__ int sdata[256];
    int base = blockIdx.x * 1024;
    int t = threadIdx.x;
    int s = 0;
    #pragma unroll
    for (int j = 0; j < 4; j++) {
        int i = base + t * 4 + j;
        if (i < n) s += cnt[i];
    }
    sdata[t] = s;
    __syncthreads();
    for (int off = 128; off > 0; off >>= 1) {
        if (t < off) sdata[t] += sdata[t + off];
        __syncthreads();
    }
    if (t == 0) bsum[blockIdx.x] = sdata[0];
}

__global__ void scan2_k(int* bsum, int nb) {
    if (threadIdx.x == 0 && blockIdx.x == 0) {
        int run = 0;
        for (int b = 0; b < nb; b++) { int v = bsum[b]; bsum[b] = run; run += v; }
    }
}

__global__ __launch_bounds__(256) void scan3_k(const int* __restrict__ cnt, const int* __restrict__ bsum,
                                               int* row_ptr, int n) {
    __shared__ int sdata[256];
    int base = blockIdx.x * 1024;
    int t = threadIdx.x;
    int loc[4];
    int s = 0;
    #pragma unroll
    for (int j = 0; j < 4; j++) {
        int i = base + t * 4 + j;
        loc[j] = (i < n) ? cnt[i] : 0;
        s += loc[j];
    }
    sdata[t] = s;
    __syncthreads();
    for (int off = 1; off < 256; off <<= 1) {
        int v = (t >= off) ? sdata[t - off] : 0;
        __syncthreads();
        sdata[t] += v;
        __syncthreads();
    }
    int excl = sdata[t] - s;
    int run = bsum[blockIdx.x] + excl;
    #pragma unroll
    for (int j = 0; j < 4; j++) {
        int i = base + t * 4 + j;
        if (i < n) row_ptr[i] = run;
        run += loc[j];
    }
}

__global__ __launch_bounds__(256) void fill_k(const int* __restrict__ src, const int* __restrict__ dst,
                                              const float* __restrict__ ew,
                                              const int* __restrict__ row_ptr,
                                              const int* __restrict__ rank,
                                              int2* __restrict__ meta, int E) {
    int e = blockIdx.x * 256 + threadIdx.x;
    if (e < E) {
        int d = dst[e];
        int pos = row_ptr[d] + rank[e];
        meta[pos] = make_int2(src[e], __float_as_int(ew[e]));
    }
}

__global__ __launch_bounds__(256) void deg_k(const int2* __restrict__ meta,
                                             const int* __restrict__ row_ptr,
                                             const int* __restrict__ cnt,
                                             float* __restrict__ dinv, int n) {
    int d = blockIdx.x * 256 + threadIdx.x;
    if (d < n) {
        int start = row_ptr[d];
        int c = cnt[d];
        float s = 1.0f;
        for (int j = 0; j < c; j++) s += __int_as_float(meta[start + j].y);
        dinv[d] = rsqrtf(s);
    }
}

__global__ __launch_bounds__(256) void scale_k(int2* __restrict__ meta,
                                               const float* __restrict__ dinv, int E) {
    int e = blockIdx.x * 256 + threadIdx.x;
    if (e < E) {
        int2 m = meta[e];
        float wn = __int_as_float(m.y) * dinv[m.x];
        ((int*)meta)[2 * e + 1] = __float_as_int(wn);
    }
}

// ---------------- fp32 GEMM: T[M,128] = A[M,K] @ W[K,128] ----------------
// BM=128, BN=128, BK=32, 256 threads, 8x8 outputs/thread.
// A staged TRANSPOSED (xs[k][m]) so both fragments load as float4.

#define BM 128
#define BN 128
#define BK 32

__global__ __launch_bounds__(256) void gemm_k(const float* __restrict__ A, const float* __restrict__ W,
                                              float* __restrict__ T, int M, int K) {
    __shared__ float xs[BK][BM + 4];   // [k][m], +4 pad spreads transpose-write banks
    __shared__ float ws[BK][BN];       // [k][n]
    int tid = threadIdx.x;
    int row0 = blockIdx.x * BM;
    int tx = tid & 15;    // n0 = tx*8
    int ty = tid >> 4;    // m0 = ty*8
    float acc[8][8] = {};

    for (int k0 = 0; k0 < K; k0 += BK) {
        // stage A tile 128x32, transposed into xs[k][m]
        #pragma unroll
        for (int j = 0; j < 4; j++) {
            int idx = tid + j * 256;          // 0..1023 float4 slots
            int m = idx >> 3;                 // 8 float4 per A-row
            int kq = (idx & 7) << 2;
            int gm = row0 + m;
            float4 v = make_float4(0.f, 0.f, 0.f, 0.f);
            if (gm < M) v = *(const float4*)(A + (size_t)gm * K + k0 + kq);
            xs[kq + 0][m] = v.x;
            xs[kq + 1][m] = v.y;
            xs[kq + 2][m] = v.z;
            xs[kq + 3][m] = v.w;
        }
        // stage W tile 32x128 (row copy)
        #pragma unroll
        for (int j = 0; j < 4; j++) {
            int idx = tid + j * 256;
            int kk = idx >> 5;                // 32 float4 per W-row
            int c = (idx & 31) << 2;
            *(float4*)(&ws[kk][c]) = *(const float4*)(W + (size_t)(k0 + kk) * BN + c);
        }
        __syncthreads();
        #pragma unroll 4
        for (int k = 0; k < BK; k++) {
            float4 a0 = *(const float4*)(&xs[k][ty * 8]);
            float4 a1 = *(const float4*)(&xs[k][ty * 8 + 4]);
            float4 b0 = *(const float4*)(&ws[k][tx * 8]);
            float4 b1 = *(const float4*)(&ws[k][tx * 8 + 4]);
            float a[8] = {a0.x, a0.y, a0.z, a0.w, a1.x, a1.y, a1.z, a1.w};
            float b[8] = {b0.x, b0.y, b0.z, b0.w, b1.x, b1.y, b1.z, b1.w};
            #pragma unroll
            for (int r = 0; r < 8; r++) {
                #pragma unroll
                for (int c = 0; c < 8; c++) {
                    acc[r][c] = fmaf(a[r], b[c], acc[r][c]);
                }
            }
        }
        __syncthreads();
    }
    #pragma unroll
    for (int r = 0; r < 8; r++) {
        int gm = row0 + ty * 8 + r;
        if (gm < M) {
            *(float4*)(T + (size_t)gm * BN + tx * 8)     = *(float4*)(&acc[r][0]);
            *(float4*)(T + (size_t)gm * BN + tx * 8 + 4) = *(float4*)(&acc[r][4]);
        }
    }
}

// ---------------- aggregation + bias + relu ----------------

__global__ __launch_bounds__(128) void agg_k(const float* __restrict__ T, float* __restrict__ H,
                                             const int2* __restrict__ meta,
                                             const int* __restrict__ row_ptr, const int* __restrict__ cnt,
                                             const float* __restrict__ dinv, const float* __restrict__ bias,
                                             int n) {
    int d = blockIdx.x;
    int f = threadIdx.x;
    float nd = dinv[d];
    float acc = nd * T[(size_t)d * 128 + f];
    int start = row_ptr[d];
    int c = cnt[d];
    int j = 0;
    for (; j + 1 < c; j += 2) {
        int2 m0 = meta[start + j];
        int2 m1 = meta[start + j + 1];
        float t0 = T[(size_t)m0.x * 128 + f];
        float t1 = T[(size_t)m1.x * 128 + f];
        acc = fmaf(__int_as_float(m0.y), t0, acc);
        acc = fmaf(__int_as_float(m1.y), t1, acc);
    }
    if (j < c) {
        int2 m0 = meta[start + j];
        acc = fmaf(__int_as_float(m0.y), T[(size_t)m0.x * 128 + f], acc);
    }
    float v = fmaf(nd, acc, bias[f]);
    H[(size_t)d * 128 + f] = v > 0.f ? v : 0.f;
}

// ---------------- final FC(128->10) + softmax ----------------

__global__ __launch_bounds__(256) void fc_k(const float* __restrict__ Hb, const float* __restrict__ FW,
                                            const float* __restrict__ FB, float* __restrict__ out, int n) {
    __shared__ float fw[128 * 10];
    __shared__ float fb[16];
    int tid = threadIdx.x;
    for (int i = tid; i < 128 * 10; i += 256) fw[i] = FW[i];
    if (tid < 10) fb[tid] = FB[tid];
    __syncthreads();
    int wave = tid >> 6, lane = tid & 63;
    int r = blockIdx.x * 4 + wave;
    if (r >= n) return;
    float h0 = Hb[(size_t)r * 128 + lane];
    float h1 = Hb[(size_t)r * 128 + 64 + lane];
    float p[10];
    #pragma unroll
    for (int c = 0; c < 10; c++)
        p[c] = h0 * fw[lane * 10 + c] + h1 * fw[(64 + lane) * 10 + c];
    #pragma unroll
    for (int off = 32; off > 0; off >>= 1) {
        #pragma unroll
        for (int c = 0; c < 10; c++) p[c] += __shfl_xor(p[c], off);
    }
    float m = -1e30f;
    #pragma unroll
    for (int c = 0; c < 10; c++) { p[c] += fb[c]; m = fmaxf(m, p[c]); }
    float s = 0.f;
    float e[10];
    #pragma unroll
    for (int c = 0; c < 10; c++) { e[c] = __expf(p[c] - m); s += e[c]; }
    float inv = 1.f / s;
    if (lane < 10) out[(size_t)r * 10 + lane] = e[lane] * inv;
}

// ---------------- host ----------------

extern "C" void kernel_launch(void* const* d_in, const int* in_sizes, int n_in,
                              void* d_out, int out_size, void* d_ws, size_t ws_size,
                              hipStream_t stream) {
    const float* x  = (const float*)d_in[0];
    const int*   ei = (const int*)d_in[1];
    const float* ew = (const float*)d_in[2];
    const float* W1 = (const float*)d_in[3];
    const float* b1 = (const float*)d_in[4];
    const float* W2 = (const float*)d_in[5];
    const float* b2 = (const float*)d_in[6];
    const float* W3 = (const float*)d_in[7];
    const float* b3 = (const float*)d_in[8];
    const float* FW = (const float*)d_in[9];
    const float* FB = (const float*)d_in[10];
    float* out = (float*)d_out;

    int Hd = in_sizes[4];            // 128
    int F  = in_sizes[3] / Hd;       // 256
    int N  = in_sizes[0] / F;        // 50000
    int E  = in_sizes[1] / 2;        // 800000

    const int* src = ei;
    const int* dst = ei + E;

    char* ws = (char*)d_ws;
    size_t off = 0;
    auto alloc = [&](size_t bytes) -> void* {
        void* p = ws + off;
        off = (off + bytes + 255) & ~(size_t)255;
        return p;
    };
    float* dinv    = (float*)alloc((size_t)N * 4);
    int*   cnt     = (int*)alloc((size_t)N * 4);
    int*   row_ptr = (int*)alloc((size_t)N * 4);
    int*   rank    = (int*)alloc((size_t)E * 4);
    int*   bsum    = (int*)alloc(4096);
    int2*  meta    = (int2*)alloc((size_t)E * 8);
    float* T       = (float*)alloc((size_t)N * Hd * 4);
    float* Hbuf    = (float*)alloc((size_t)N * Hd * 4);

    int nb = (N + 1023) / 1024;

    hipMemsetAsync(cnt, 0, (size_t)N * 4, stream);
    rank_k<<<(E + 255) / 256, 256, 0, stream>>>(dst, cnt, rank, E);
    scan1_k<<<nb, 256, 0, stream>>>(cnt, bsum, N);
    scan2_k<<<1, 64, 0, stream>>>(bsum, nb);
    scan3_k<<<nb, 256, 0, stream>>>(cnt, bsum, row_ptr, N);
    fill_k<<<(E + 255) / 256, 256, 0, stream>>>(src, dst, ew, row_ptr, rank, meta, E);
    deg_k<<<(N + 255) / 256, 256, 0, stream>>>(meta, row_ptr, cnt, dinv, N);
    scale_k<<<(E + 255) / 256, 256, 0, stream>>>(meta, dinv, E);

    int gb = (N + BM - 1) / BM;
    // layer 1
    gemm_k<<<gb, 256, 0, stream>>>(x, W1, T, N, F);
    agg_k<<<N, 128, 0, stream>>>(T, Hbuf, meta, row_ptr, cnt, dinv, b1, N);
    // layer 2
    gemm_k<<<gb, 256, 0, stream>>>(Hbuf, W2, T, N, Hd);
    agg_k<<<N, 128, 0, stream>>>(T, Hbuf, meta, row_ptr, cnt, dinv, b2, N);
    // layer 3
    gemm_k<<<gb, 256, 0, stream>>>(Hbuf, W3, T, N, Hd);
    agg_k<<<N, 128, 0, stream>>>(T, Hbuf, meta, row_ptr, cnt, dinv, b3, N);
    // FC + softmax
    fc_k<<<(N + 3) / 4, 256, 0, stream>>>(Hbuf, FW, FB, out, N);
}

// Round 4
// 522.849 us; speedup vs baseline: 1.0357x; 1.0357x over previous
//
#include <hip/hip_runtime.h>
#include <math.h>

// ---------------- CSR build (single-atomic counting sort) ----------------

__global__ __launch_bounds__(256) void rank_k(const int* __restrict__ dst, int* cnt,
                                              int* __restrict__ rank, int E) {
    int e = blockIdx.x * 256 + threadIdx.x;
    if (e < E) {
        int d = dst[e];
        rank[e] = atomicAdd(&cnt[d], 1);
    }
}

__global__ __launch_bounds__(256) void scan1_k(const int* __restrict__ cnt, int* bsum, int n) {
    __shared__ int sdata[256];
    int base = blockIdx.x * 1024;
    int t = threadIdx.x;
    int s = 0;
    #pragma unroll
    for (int j = 0; j < 4; j++) {
        int i = base + t * 4 + j;
        if (i < n) s += cnt[i];
    }
    sdata[t] = s;
    __syncthreads();
    for (int off = 128; off > 0; off >>= 1) {
        if (t < off) sdata[t] += sdata[t + off];
        __syncthreads();
    }
    if (t == 0) bsum[blockIdx.x] = sdata[0];
}

__global__ void scan2_k(int* bsum, int nb) {
    if (threadIdx.x == 0 && blockIdx.x == 0) {
        int run = 0;
        for (int b = 0; b < nb; b++) { int v = bsum[b]; bsum[b] = run; run += v; }
    }
}

__global__ __launch_bounds__(256) void scan3_k(const int* __restrict__ cnt, const int* __restrict__ bsum,
                                               int* row_ptr, int n) {
    __shared__ int sdata[256];
    int base = blockIdx.x * 1024;
    int t = threadIdx.x;
    int loc[4];
    int s = 0;
    #pragma unroll
    for (int j = 0; j < 4; j++) {
        int i = base + t * 4 + j;
        loc[j] = (i < n) ? cnt[i] : 0;
        s += loc[j];
    }
    sdata[t] = s;
    __syncthreads();
    for (int off = 1; off < 256; off <<= 1) {
        int v = (t >= off) ? sdata[t - off] : 0;
        __syncthreads();
        sdata[t] += v;
        __syncthreads();
    }
    int excl = sdata[t] - s;
    int run = bsum[blockIdx.x] + excl;
    #pragma unroll
    for (int j = 0; j < 4; j++) {
        int i = base + t * 4 + j;
        if (i < n) row_ptr[i] = run;
        run += loc[j];
    }
}

__global__ __launch_bounds__(256) void fill_k(const int* __restrict__ src, const int* __restrict__ dst,
                                              const float* __restrict__ ew,
                                              const int* __restrict__ row_ptr,
                                              const int* __restrict__ rank,
                                              int2* __restrict__ meta, int E) {
    int e = blockIdx.x * 256 + threadIdx.x;
    if (e < E) {
        int d = dst[e];
        int pos = row_ptr[d] + rank[e];
        meta[pos] = make_int2(src[e], __float_as_int(ew[e]));
    }
}

__global__ __launch_bounds__(256) void deg_k(const int2* __restrict__ meta,
                                             const int* __restrict__ row_ptr,
                                             const int* __restrict__ cnt,
                                             float* __restrict__ dinv, int n) {
    int d = blockIdx.x * 256 + threadIdx.x;
    if (d < n) {
        int start = row_ptr[d];
        int c = cnt[d];
        float s = 1.0f;
        for (int j = 0; j < c; j++) s += __int_as_float(meta[start + j].y);
        dinv[d] = rsqrtf(s);
    }
}

__global__ __launch_bounds__(256) void scale_k(int2* __restrict__ meta,
                                               const float* __restrict__ dinv, int E) {
    int e = blockIdx.x * 256 + threadIdx.x;
    if (e < E) {
        int2 m = meta[e];
        float wn = __int_as_float(m.y) * dinv[m.x];
        ((int*)meta)[2 * e + 1] = __float_as_int(wn);
    }
}

// ---------------- fp32 GEMM: T[M,128] = A[M,K] @ W[K,128] ----------------
// BM=64, BN=128, BK=32, 512 threads (8 waves), thread tile 4x4.
// Row-major A staging (conflict-free); occupancy: 3 blocks/CU x 8 waves = 75%.

#define BM 64
#define BN 128
#define BK 32

__global__ __launch_bounds__(512) void gemm_k(const float* __restrict__ A, const float* __restrict__ W,
                                              float* __restrict__ T, int M, int K) {
    __shared__ float xs[BM][BK + 4];   // [m][k], row-major
    __shared__ float ws[BK][BN];       // [k][n]
    int tid = threadIdx.x;
    int row0 = blockIdx.x * BM;
    int tx = tid & 31;    // n0 = tx*4
    int ty = tid >> 5;    // m0 = ty*4  (0..15)
    float acc[4][4] = {};

    for (int k0 = 0; k0 < K; k0 += BK) {
        // stage A tile 64x32: one float4 per thread
        {
            int m  = tid >> 3;            // 0..63
            int kq = (tid & 7) << 2;      // 0,4,...,28
            int gm = row0 + m;
            float4 v = make_float4(0.f, 0.f, 0.f, 0.f);
            if (gm < M) v = *(const float4*)(A + (size_t)gm * K + k0 + kq);
            *(float4*)(&xs[m][kq]) = v;
        }
        // stage W tile 32x128: two float4 per thread
        #pragma unroll
        for (int j = 0; j < 2; j++) {
            int idx = tid + j * 512;      // 0..1023
            int kk = idx >> 5;
            int c = (idx & 31) << 2;
            *(float4*)(&ws[kk][c]) = *(const float4*)(W + (size_t)(k0 + kk) * BN + c);
        }
        __syncthreads();
        #pragma unroll 8
        for (int k = 0; k < BK; k++) {
            float4 b = *(const float4*)(&ws[k][tx << 2]);
            float a0 = xs[ty * 4 + 0][k];
            float a1 = xs[ty * 4 + 1][k];
            float a2 = xs[ty * 4 + 2][k];
            float a3 = xs[ty * 4 + 3][k];
            acc[0][0] = fmaf(a0, b.x, acc[0][0]);
            acc[0][1] = fmaf(a0, b.y, acc[0][1]);
            acc[0][2] = fmaf(a0, b.z, acc[0][2]);
            acc[0][3] = fmaf(a0, b.w, acc[0][3]);
            acc[1][0] = fmaf(a1, b.x, acc[1][0]);
            acc[1][1] = fmaf(a1, b.y, acc[1][1]);
            acc[1][2] = fmaf(a1, b.z, acc[1][2]);
            acc[1][3] = fmaf(a1, b.w, acc[1][3]);
            acc[2][0] = fmaf(a2, b.x, acc[2][0]);
            acc[2][1] = fmaf(a2, b.y, acc[2][1]);
            acc[2][2] = fmaf(a2, b.z, acc[2][2]);
            acc[2][3] = fmaf(a2, b.w, acc[2][3]);
            acc[3][0] = fmaf(a3, b.x, acc[3][0]);
            acc[3][1] = fmaf(a3, b.y, acc[3][1]);
            acc[3][2] = fmaf(a3, b.z, acc[3][2]);
            acc[3][3] = fmaf(a3, b.w, acc[3][3]);
        }
        __syncthreads();
    }
    #pragma unroll
    for (int r = 0; r < 4; r++) {
        int gm = row0 + ty * 4 + r;
        if (gm < M) *(float4*)(T + (size_t)gm * BN + (tx << 2)) = *(float4*)(&acc[r][0]);
    }
}

// ---------------- aggregation + bias + relu ----------------

__global__ __launch_bounds__(128) void agg_k(const float* __restrict__ T, float* __restrict__ H,
                                             const int2* __restrict__ meta,
                                             const int* __restrict__ row_ptr, const int* __restrict__ cnt,
                                             const float* __restrict__ dinv, const float* __restrict__ bias,
                                             int n) {
    int d = blockIdx.x;
    int f = threadIdx.x;
    float nd = dinv[d];
    float acc = nd * T[(size_t)d * 128 + f];
    int start = row_ptr[d];
    int c = cnt[d];
    int j = 0;
    for (; j + 1 < c; j += 2) {
        int2 m0 = meta[start + j];
        int2 m1 = meta[start + j + 1];
        float t0 = T[(size_t)m0.x * 128 + f];
        float t1 = T[(size_t)m1.x * 128 + f];
        acc = fmaf(__int_as_float(m0.y), t0, acc);
        acc = fmaf(__int_as_float(m1.y), t1, acc);
    }
    if (j < c) {
        int2 m0 = meta[start + j];
        acc = fmaf(__int_as_float(m0.y), T[(size_t)m0.x * 128 + f], acc);
    }
    float v = fmaf(nd, acc, bias[f]);
    H[(size_t)d * 128 + f] = v > 0.f ? v : 0.f;
}

// ---------------- final FC(128->10) + softmax ----------------

__global__ __launch_bounds__(256) void fc_k(const float* __restrict__ Hb, const float* __restrict__ FW,
                                            const float* __restrict__ FB, float* __restrict__ out, int n) {
    __shared__ float fw[128 * 10];
    __shared__ float fb[16];
    int tid = threadIdx.x;
    for (int i = tid; i < 128 * 10; i += 256) fw[i] = FW[i];
    if (tid < 10) fb[tid] = FB[tid];
    __syncthreads();
    int wave = tid >> 6, lane = tid & 63;
    int r = blockIdx.x * 4 + wave;
    if (r >= n) return;
    float h0 = Hb[(size_t)r * 128 + lane];
    float h1 = Hb[(size_t)r * 128 + 64 + lane];
    float p[10];
    #pragma unroll
    for (int c = 0; c < 10; c++)
        p[c] = h0 * fw[lane * 10 + c] + h1 * fw[(64 + lane) * 10 + c];
    #pragma unroll
    for (int off = 32; off > 0; off >>= 1) {
        #pragma unroll
        for (int c = 0; c < 10; c++) p[c] += __shfl_xor(p[c], off);
    }
    float m = -1e30f;
    #pragma unroll
    for (int c = 0; c < 10; c++) { p[c] += fb[c]; m = fmaxf(m, p[c]); }
    float s = 0.f;
    float e[10];
    #pragma unroll
    for (int c = 0; c < 10; c++) { e[c] = __expf(p[c] - m); s += e[c]; }
    float inv = 1.f / s;
    if (lane < 10) out[(size_t)r * 10 + lane] = e[lane] * inv;
}

// ---------------- host ----------------

extern "C" void kernel_launch(void* const* d_in, const int* in_sizes, int n_in,
                              void* d_out, int out_size, void* d_ws, size_t ws_size,
                              hipStream_t stream) {
    const float* x  = (const float*)d_in[0];
    const int*   ei = (const int*)d_in[1];
    const float* ew = (const float*)d_in[2];
    const float* W1 = (const float*)d_in[3];
    const float* b1 = (const float*)d_in[4];
    const float* W2 = (const float*)d_in[5];
    const float* b2 = (const float*)d_in[6];
    const float* W3 = (const float*)d_in[7];
    const float* b3 = (const float*)d_in[8];
    const float* FW = (const float*)d_in[9];
    const float* FB = (const float*)d_in[10];
    float* out = (float*)d_out;

    int Hd = in_sizes[4];            // 128
    int F  = in_sizes[3] / Hd;       // 256
    int N  = in_sizes[0] / F;        // 50000
    int E  = in_sizes[1] / 2;        // 800000

    const int* src = ei;
    const int* dst = ei + E;

    char* ws = (char*)d_ws;
    size_t off = 0;
    auto alloc = [&](size_t bytes) -> void* {
        void* p = ws + off;
        off = (off + bytes + 255) & ~(size_t)255;
        return p;
    };
    float* dinv    = (float*)alloc((size_t)N * 4);
    int*   cnt     = (int*)alloc((size_t)N * 4);
    int*   row_ptr = (int*)alloc((size_t)N * 4);
    int*   rank    = (int*)alloc((size_t)E * 4);
    int*   bsum    = (int*)alloc(4096);
    int2*  meta    = (int2*)alloc((size_t)E * 8);
    float* T       = (float*)alloc((size_t)N * Hd * 4);
    float* Hbuf    = (float*)alloc((size_t)N * Hd * 4);

    int nb = (N + 1023) / 1024;

    hipMemsetAsync(cnt, 0, (size_t)N * 4, stream);
    rank_k<<<(E + 255) / 256, 256, 0, stream>>>(dst, cnt, rank, E);
    scan1_k<<<nb, 256, 0, stream>>>(cnt, bsum, N);
    scan2_k<<<1, 64, 0, stream>>>(bsum, nb);
    scan3_k<<<nb, 256, 0, stream>>>(cnt, bsum, row_ptr, N);
    fill_k<<<(E + 255) / 256, 256, 0, stream>>>(src, dst, ew, row_ptr, rank, meta, E);
    deg_k<<<(N + 255) / 256, 256, 0, stream>>>(meta, row_ptr, cnt, dinv, N);
    scale_k<<<(E + 255) / 256, 256, 0, stream>>>(meta, dinv, E);

    int gb = (N + BM - 1) / BM;
    // layer 1
    gemm_k<<<gb, 512, 0, stream>>>(x, W1, T, N, F);
    agg_k<<<N, 128, 0, stream>>>(T, Hbuf, meta, row_ptr, cnt, dinv, b1, N);
    // layer 2
    gemm_k<<<gb, 512, 0, stream>>>(Hbuf, W2, T, N, Hd);
    agg_k<<<N, 128, 0, stream>>>(T, Hbuf, meta, row_ptr, cnt, dinv, b2, N);
    // layer 3
    gemm_k<<<gb, 512, 0, stream>>>(Hbuf, W3, T, N, Hd);
    agg_k<<<N, 128, 0, stream>>>(T, Hbuf, meta, row_ptr, cnt, dinv, b3, N);
    // FC + softmax
    fc_k<<<(N + 3) / 4, 256, 0, stream>>>(Hbuf, FW, FB, out, N);
}

// Round 6
// 474.831 us; speedup vs baseline: 1.1405x; 1.1011x over previous
//
#include <hip/hip_runtime.h>
#include <hip/hip_fp16.h>
#include <math.h>

// ---------------- CSR build (single-atomic counting sort) ----------------

__global__ __launch_bounds__(256) void rank_k(const int* __restrict__ dst, int* cnt,
                                              int* __restrict__ rank, int E) {
    int e = blockIdx.x * 256 + threadIdx.x;
    if (e < E) {
        int d = dst[e];
        rank[e] = atomicAdd(&cnt[d], 1);
    }
}

__global__ __launch_bounds__(256) void scan1_k(const int* __restrict__ cnt, int* bsum, int n) {
    __shared__ int sdata[256];
    int base = blockIdx.x * 1024;
    int t = threadIdx.x;
    int s = 0;
    #pragma unroll
    for (int j = 0; j < 4; j++) {
        int i = base + t * 4 + j;
        if (i < n) s += cnt[i];
    }
    sdata[t] = s;
    __syncthreads();
    for (int off = 128; off > 0; off >>= 1) {
        if (t < off) sdata[t] += sdata[t + off];
        __syncthreads();
    }
    if (t == 0) bsum[blockIdx.x] = sdata[0];
}

__global__ void scan2_k(int* bsum, int nb) {
    if (threadIdx.x == 0 && blockIdx.x == 0) {
        int run = 0;
        for (int b = 0; b < nb; b++) { int v = bsum[b]; bsum[b] = run; run += v; }
    }
}

__global__ __launch_bounds__(256) void scan3_k(const int* __restrict__ cnt, const int* __restrict__ bsum,
                                               int* row_ptr, int n) {
    __shared__ int sdata[256];
    int base = blockIdx.x * 1024;
    int t = threadIdx.x;
    int loc[4];
    int s = 0;
    #pragma unroll
    for (int j = 0; j < 4; j++) {
        int i = base + t * 4 + j;
        loc[j] = (i < n) ? cnt[i] : 0;
        s += loc[j];
    }
    sdata[t] = s;
    __syncthreads();
    for (int off = 1; off < 256; off <<= 1) {
        int v = (t >= off) ? sdata[t - off] : 0;
        __syncthreads();
        sdata[t] += v;
        __syncthreads();
    }
    int excl = sdata[t] - s;
    int run = bsum[blockIdx.x] + excl;
    #pragma unroll
    for (int j = 0; j < 4; j++) {
        int i = base + t * 4 + j;
        if (i < n) row_ptr[i] = run;
        run += loc[j];
    }
}

__global__ __launch_bounds__(256) void fill_k(const int* __restrict__ src, const int* __restrict__ dst,
                                              const float* __restrict__ ew,
                                              const int* __restrict__ row_ptr,
                                              const int* __restrict__ rank,
                                              int2* __restrict__ meta, int E) {
    int e = blockIdx.x * 256 + threadIdx.x;
    if (e < E) {
        int d = dst[e];
        int pos = row_ptr[d] + rank[e];
        meta[pos] = make_int2(src[e], __float_as_int(ew[e]));
    }
}

__global__ __launch_bounds__(256) void deg_k(const int2* __restrict__ meta,
                                             const int* __restrict__ row_ptr,
                                             const int* __restrict__ cnt,
                                             float* __restrict__ dinv, int n) {
    int d = blockIdx.x * 256 + threadIdx.x;
    if (d < n) {
        int start = row_ptr[d];
        int c = cnt[d];
        float s = 1.0f;
        for (int j = 0; j < c; j++) s += __int_as_float(meta[start + j].y);
        dinv[d] = rsqrtf(s);
    }
}

__global__ __launch_bounds__(256) void scale_k(int2* __restrict__ meta,
                                               const float* __restrict__ dinv, int E) {
    int e = blockIdx.x * 256 + threadIdx.x;
    if (e < E) {
        int2 m = meta[e];
        float wn = __int_as_float(m.y) * dinv[m.x];
        ((int*)meta)[2 * e + 1] = __float_as_int(wn);
    }
}

// ---------------- fp32 GEMM: T[M,128] = A[M,K] @ W[K,128], T stored fp16 ----
// BM=64, BN=128, BK=32, 512 threads (8 waves), thread tile 4x4.

#define BM 64
#define BN 128
#define BK 32

__global__ __launch_bounds__(512) void gemm_k(const float* __restrict__ A, const float* __restrict__ W,
                                              __half* __restrict__ T, int M, int K) {
    __shared__ float xs[BM][BK + 4];   // [m][k], row-major
    __shared__ float ws[BK][BN];       // [k][n]
    int tid = threadIdx.x;
    int row0 = blockIdx.x * BM;
    int tx = tid & 31;    // n0 = tx*4
    int ty = tid >> 5;    // m0 = ty*4  (0..15)
    float acc[4][4] = {};

    for (int k0 = 0; k0 < K; k0 += BK) {
        {
            int m  = tid >> 3;            // 0..63
            int kq = (tid & 7) << 2;      // 0,4,...,28
            int gm = row0 + m;
            float4 v = make_float4(0.f, 0.f, 0.f, 0.f);
            if (gm < M) v = *(const float4*)(A + (size_t)gm * K + k0 + kq);
            *(float4*)(&xs[m][kq]) = v;
        }
        #pragma unroll
        for (int j = 0; j < 2; j++) {
            int idx = tid + j * 512;      // 0..1023
            int kk = idx >> 5;
            int c = (idx & 31) << 2;
            *(float4*)(&ws[kk][c]) = *(const float4*)(W + (size_t)(k0 + kk) * BN + c);
        }
        __syncthreads();
        #pragma unroll 8
        for (int k = 0; k < BK; k++) {
            float4 b = *(const float4*)(&ws[k][tx << 2]);
            float a0 = xs[ty * 4 + 0][k];
            float a1 = xs[ty * 4 + 1][k];
            float a2 = xs[ty * 4 + 2][k];
            float a3 = xs[ty * 4 + 3][k];
            acc[0][0] = fmaf(a0, b.x, acc[0][0]);
            acc[0][1] = fmaf(a0, b.y, acc[0][1]);
            acc[0][2] = fmaf(a0, b.z, acc[0][2]);
            acc[0][3] = fmaf(a0, b.w, acc[0][3]);
            acc[1][0] = fmaf(a1, b.x, acc[1][0]);
            acc[1][1] = fmaf(a1, b.y, acc[1][1]);
            acc[1][2] = fmaf(a1, b.z, acc[1][2]);
            acc[1][3] = fmaf(a1, b.w, acc[1][3]);
            acc[2][0] = fmaf(a2, b.x, acc[2][0]);
            acc[2][1] = fmaf(a2, b.y, acc[2][1]);
            acc[2][2] = fmaf(a2, b.z, acc[2][2]);
            acc[2][3] = fmaf(a2, b.w, acc[2][3]);
            acc[3][0] = fmaf(a3, b.x, acc[3][0]);
            acc[3][1] = fmaf(a3, b.y, acc[3][1]);
            acc[3][2] = fmaf(a3, b.z, acc[3][2]);
            acc[3][3] = fmaf(a3, b.w, acc[3][3]);
        }
        __syncthreads();
    }
    #pragma unroll
    for (int r = 0; r < 4; r++) {
        int gm = row0 + ty * 4 + r;
        if (gm < M) {
            __half2 h0 = __floats2half2_rn(acc[r][0], acc[r][1]);
            __half2 h1 = __floats2half2_rn(acc[r][2], acc[r][3]);
            __half2* p = (__half2*)(T + (size_t)gm * BN + (tx << 2));
            p[0] = h0;
            p[1] = h1;
        }
    }
}

// ---------------- aggregation + bias + relu (wave per node, fp16 gather) ----

__global__ __launch_bounds__(256) void agg_k(const __half2* __restrict__ Th, float* __restrict__ H,
                                             const int2* __restrict__ meta,
                                             const int* __restrict__ row_ptr, const int* __restrict__ cnt,
                                             const float* __restrict__ dinv, const float* __restrict__ bias,
                                             int n) {
    int wave = threadIdx.x >> 6, lane = threadIdx.x & 63;
    int d = blockIdx.x * 4 + wave;
    if (d >= n) return;
    float nd = dinv[d];
    float2 ts = __half22float2(Th[(size_t)d * 64 + lane]);
    float ax = nd * ts.x;
    float ay = nd * ts.y;
    int start = row_ptr[d];
    int c = cnt[d];
    int j = 0;
    for (; j + 1 < c; j += 2) {
        int2 m0 = meta[start + j];
        int2 m1 = meta[start + j + 1];
        float2 t0 = __half22float2(Th[(size_t)m0.x * 64 + lane]);
        float2 t1 = __half22float2(Th[(size_t)m1.x * 64 + lane]);
        float w0 = __int_as_float(m0.y);
        float w1 = __int_as_float(m1.y);
        ax = fmaf(w0, t0.x, ax);
        ay = fmaf(w0, t0.y, ay);
        ax = fmaf(w1, t1.x, ax);
        ay = fmaf(w1, t1.y, ay);
    }
    if (j < c) {
        int2 m0 = meta[start + j];
        float2 t0 = __half22float2(Th[(size_t)m0.x * 64 + lane]);
        float w0 = __int_as_float(m0.y);
        ax = fmaf(w0, t0.x, ax);
        ay = fmaf(w0, t0.y, ay);
    }
    float2 bb = *(const float2*)(bias + 2 * lane);
    float vx = fmaf(nd, ax, bb.x);
    float vy = fmaf(nd, ay, bb.y);
    float2 o;
    o.x = vx > 0.f ? vx : 0.f;
    o.y = vy > 0.f ? vy : 0.f;
    *(float2*)(H + (size_t)d * 128 + 2 * lane) = o;
}

// ---------------- final FC(128->10) + softmax ----------------

__global__ __launch_bounds__(256) void fc_k(const float* __restrict__ Hb, const float* __restrict__ FW,
                                            const float* __restrict__ FB, float* __restrict__ out, int n) {
    __shared__ float fw[128 * 10];
    __shared__ float fb[16];
    int tid = threadIdx.x;
    for (int i = tid; i < 128 * 10; i += 256) fw[i] = FW[i];
    if (tid < 10) fb[tid] = FB[tid];
    __syncthreads();
    int wave = tid >> 6, lane = tid & 63;
    int r = blockIdx.x * 4 + wave;
    if (r >= n) return;
    float h0 = Hb[(size_t)r * 128 + lane];
    float h1 = Hb[(size_t)r * 128 + 64 + lane];
    float p[10];
    #pragma unroll
    for (int c = 0; c < 10; c++)
        p[c] = h0 * fw[lane * 10 + c] + h1 * fw[(64 + lane) * 10 + c];
    #pragma unroll
    for (int off = 32; off > 0; off >>= 1) {
        #pragma unroll
        for (int c = 0; c < 10; c++) p[c] += __shfl_xor(p[c], off);
    }
    float m = -1e30f;
    #pragma unroll
    for (int c = 0; c < 10; c++) { p[c] += fb[c]; m = fmaxf(m, p[c]); }
    float s = 0.f;
    float e[10];
    #pragma unroll
    for (int c = 0; c < 10; c++) { e[c] = __expf(p[c] - m); s += e[c]; }
    float inv = 1.f / s;
    if (lane < 10) out[(size_t)r * 10 + lane] = e[lane] * inv;
}

// ---------------- host ----------------

extern "C" void kernel_launch(void* const* d_in, const int* in_sizes, int n_in,
                              void* d_out, int out_size, void* d_ws, size_t ws_size,
                              hipStream_t stream) {
    const float* x  = (const float*)d_in[0];
    const int*   ei = (const int*)d_in[1];
    const float* ew = (const float*)d_in[2];
    const float* W1 = (const float*)d_in[3];
    const float* b1 = (const float*)d_in[4];
    const float* W2 = (const float*)d_in[5];
    const float* b2 = (const float*)d_in[6];
    const float* W3 = (const float*)d_in[7];
    const float* b3 = (const float*)d_in[8];
    const float* FW = (const float*)d_in[9];
    const float* FB = (const float*)d_in[10];
    float* out = (float*)d_out;

    int Hd = in_sizes[4];            // 128
    int F  = in_sizes[3] / Hd;       // 256
    int N  = in_sizes[0] / F;        // 50000
    int E  = in_sizes[1] / 2;        // 800000

    const int* src = ei;
    const int* dst = ei + E;

    char* ws = (char*)d_ws;
    size_t off = 0;
    auto alloc = [&](size_t bytes) -> void* {
        void* p = ws + off;
        off = (off + bytes + 255) & ~(size_t)255;
        return p;
    };
    float* dinv    = (float*)alloc((size_t)N * 4);
    int*   cnt     = (int*)alloc((size_t)N * 4);
    int*   row_ptr = (int*)alloc((size_t)N * 4);
    int*   rank    = (int*)alloc((size_t)E * 4);
    int*   bsum    = (int*)alloc(4096);
    int2*  meta    = (int2*)alloc((size_t)E * 8);
    __half* T      = (__half*)alloc((size_t)N * Hd * 2);
    float* Hbuf    = (float*)alloc((size_t)N * Hd * 4);

    int nb = (N + 1023) / 1024;

    hipMemsetAsync(cnt, 0, (size_t)N * 4, stream);
    rank_k<<<(E + 255) / 256, 256, 0, stream>>>(dst, cnt, rank, E);
    scan1_k<<<nb, 256, 0, stream>>>(cnt, bsum, N);
    scan2_k<<<1, 64, 0, stream>>>(bsum, nb);
    scan3_k<<<nb, 256, 0, stream>>>(cnt, bsum, row_ptr, N);
    fill_k<<<(E + 255) / 256, 256, 0, stream>>>(src, dst, ew, row_ptr, rank, meta, E);
    deg_k<<<(N + 255) / 256, 256, 0, stream>>>(meta, row_ptr, cnt, dinv, N);
    scale_k<<<(E + 255) / 256, 256, 0, stream>>>(meta, dinv, E);

    int gb = (N + BM - 1) / BM;
    int ab = (N + 3) / 4;
    // layer 1
    gemm_k<<<gb, 512, 0, stream>>>(x, W1, T, N, F);
    agg_k<<<ab, 256, 0, stream>>>((const __half2*)T, Hbuf, meta, row_ptr, cnt, dinv, b1, N);
    // layer 2
    gemm_k<<<gb, 512, 0, stream>>>(Hbuf, W2, T, N, Hd);
    agg_k<<<ab, 256, 0, stream>>>((const __half2*)T, Hbuf, meta, row_ptr, cnt, dinv, b2, N);
    // layer 3
    gemm_k<<<gb, 512, 0, stream>>>(Hbuf, W3, T, N, Hd);
    agg_k<<<ab, 256, 0, stream>>>((const __half2*)T, Hbuf, meta, row_ptr, cnt, dinv, b3, N);
    // FC + softmax
    fc_k<<<(N + 3) / 4, 256, 0, stream>>>(Hbuf, FW, FB, out, N);
}

// Round 8
// 420.972 us; speedup vs baseline: 1.2864x; 1.1279x over previous
//
#include <hip/hip_runtime.h>
#include <hip/hip_fp16.h>
#include <math.h>

typedef _Float16 half8 __attribute__((ext_vector_type(8)));
typedef _Float16 half4v __attribute__((ext_vector_type(4)));
typedef float float4v __attribute__((ext_vector_type(4)));

// ---------------- CSR build (single-atomic counting sort) ----------------

__global__ __launch_bounds__(256) void rank_k(const int* __restrict__ dst, int* cnt,
                                              int* __restrict__ rank, int E) {
    int e = blockIdx.x * 256 + threadIdx.x;
    if (e < E) {
        int d = dst[e];
        rank[e] = atomicAdd(&cnt[d], 1);
    }
}

__global__ __launch_bounds__(256) void scan1_k(const int* __restrict__ cnt, int* bsum, int n) {
    __shared__ int sdata[256];
    int base = blockIdx.x * 1024;
    int t = threadIdx.x;
    int s = 0;
    #pragma unroll
    for (int j = 0; j < 4; j++) {
        int i = base + t * 4 + j;
        if (i < n) s += cnt[i];
    }
    sdata[t] = s;
    __syncthreads();
    for (int off = 128; off > 0; off >>= 1) {
        if (t < off) sdata[t] += sdata[t + off];
        __syncthreads();
    }
    if (t == 0) bsum[blockIdx.x] = sdata[0];
}

__global__ void scan2_k(int* bsum, int nb) {
    if (threadIdx.x == 0 && blockIdx.x == 0) {
        int run = 0;
        for (int b = 0; b < nb; b++) { int v = bsum[b]; bsum[b] = run; run += v; }
    }
}

__global__ __launch_bounds__(256) void scan3_k(const int* __restrict__ cnt, const int* __restrict__ bsum,
                                               int* row_ptr, int n) {
    __shared__ int sdata[256];
    int base = blockIdx.x * 1024;
    int t = threadIdx.x;
    int loc[4];
    int s = 0;
    #pragma unroll
    for (int j = 0; j < 4; j++) {
        int i = base + t * 4 + j;
        loc[j] = (i < n) ? cnt[i] : 0;
        s += loc[j];
    }
    sdata[t] = s;
    __syncthreads();
    for (int off = 1; off < 256; off <<= 1) {
        int v = (t >= off) ? sdata[t - off] : 0;
        __syncthreads();
        sdata[t] += v;
        __syncthreads();
    }
    int excl = sdata[t] - s;
    int run = bsum[blockIdx.x] + excl;
    #pragma unroll
    for (int j = 0; j < 4; j++) {
        int i = base + t * 4 + j;
        if (i < n) row_ptr[i] = run;
        run += loc[j];
    }
}

__global__ __launch_bounds__(256) void fill_k(const int* __restrict__ src, const int* __restrict__ dst,
                                              const float* __restrict__ ew,
                                              const int* __restrict__ row_ptr,
                                              const int* __restrict__ rank,
                                              int2* __restrict__ meta, int E) {
    int e = blockIdx.x * 256 + threadIdx.x;
    if (e < E) {
        int d = dst[e];
        int pos = row_ptr[d] + rank[e];
        meta[pos] = make_int2(src[e], __float_as_int(ew[e]));
    }
}

__global__ __launch_bounds__(256) void deg_k(const int2* __restrict__ meta,
                                             const int* __restrict__ row_ptr,
                                             const int* __restrict__ cnt,
                                             float* __restrict__ dinv, int n) {
    int d = blockIdx.x * 256 + threadIdx.x;
    if (d < n) {
        int start = row_ptr[d];
        int c = cnt[d];
        float s = 1.0f;
        for (int j = 0; j < c; j++) s += __int_as_float(meta[start + j].y);
        dinv[d] = rsqrtf(s);
    }
}

__global__ __launch_bounds__(256) void scale_k(int2* __restrict__ meta,
                                               const float* __restrict__ dinv, int E) {
    int e = blockIdx.x * 256 + threadIdx.x;
    if (e < E) {
        int2 m = meta[e];
        float wn = __int_as_float(m.y) * dinv[m.x];
        ((int*)meta)[2 * e + 1] = __float_as_int(wn);
    }
}

// ---------------- converts ----------------

__global__ __launch_bounds__(256) void cvtx_k(const float4* __restrict__ in,
                                              half4v* __restrict__ out, int n4) {
    int i = blockIdx.x * 256 + threadIdx.x;
    if (i < n4) {
        float4 v = in[i];
        half4v o = {(_Float16)v.x, (_Float16)v.y, (_Float16)v.z, (_Float16)v.w};
        out[i] = o;
    }
}

// W[K][128] fp32 -> WT[128][K] fp16, all three weight matrices in one kernel
__global__ __launch_bounds__(256) void cvtw_k(const float* __restrict__ W1, const float* __restrict__ W2,
                                              const float* __restrict__ W3,
                                              _Float16* __restrict__ T1, _Float16* __restrict__ T2,
                                              _Float16* __restrict__ T3, int F, int Hd) {
    int i = blockIdx.x * 256 + threadIdx.x;
    int n1 = F * Hd, n2 = Hd * Hd;
    if (i < n1) {
        int k = i >> 7, n = i & 127;
        T1[n * F + k] = (_Float16)W1[i];
    } else if (i < n1 + n2) {
        int j = i - n1; int k = j >> 7, n = j & 127;
        T2[n * Hd + k] = (_Float16)W2[j];
    } else if (i < n1 + 2 * n2) {
        int j = i - n1 - n2; int k = j >> 7, n = j & 127;
        T3[n * Hd + k] = (_Float16)W3[j];
    }
}

// ---------------- MFMA fp16 GEMM: T[M,128] = A[M,K] @ BT[128,K]^T ----------
// 256 threads = 4 waves. BM=64 (4 stripes of 16), BK=64.
// Wave w owns N-tiles {2w, 2w+1} across all 4 M-stripes.
// mfma_f32_16x16x32_f16; A/B use the same per-lane k mapping so any
// k-permutation cancels. C/D: col=lane&15, row=(lane>>4)*4+reg (HW-verified).

__global__ __launch_bounds__(256) void gemmh_k(const _Float16* __restrict__ A,
                                               const _Float16* __restrict__ BT,
                                               _Float16* __restrict__ T, int M, int K) {
    __shared__ __align__(16) _Float16 As[64][72];    // +8 pad: 144B row stride
    __shared__ __align__(16) _Float16 Bs[128][72];
    int tid = threadIdx.x;
    int w = tid >> 6, l = tid & 63;
    int lr = l & 15, lk = l >> 4;
    int row0 = blockIdx.x * 64;
    float4v acc[4][2];
    #pragma unroll
    for (int s = 0; s < 4; s++)
        #pragma unroll
        for (int n = 0; n < 2; n++)
            acc[s][n] = (float4v){0.f, 0.f, 0.f, 0.f};

    for (int k0 = 0; k0 < K; k0 += 64) {
        // stage A tile 64x64 halves: 512 chunks of 8 (8 chunks per row)
        #pragma unroll
        for (int j = 0; j < 2; j++) {
            int idx = tid + j * 256;          // 0..511
            int r = idx >> 3;                 // 0..63
            int c8 = (idx & 7) * 8;           // 0..56
            int gm = row0 + r;
            half8 v = {0, 0, 0, 0, 0, 0, 0, 0};
            if (gm < M) v = *(const half8*)(A + (size_t)gm * K + k0 + c8);
            *(half8*)(&As[r][c8]) = v;
        }
        // stage B tile 128x64 halves: 1024 chunks of 8
        #pragma unroll
        for (int j = 0; j < 4; j++) {
            int idx = tid + j * 256;          // 0..1023
            int r = idx >> 3;                 // 0..127
            int c8 = (idx & 7) * 8;
            *(half8*)(&Bs[r][c8]) = *(const half8*)(BT + (size_t)r * K + k0 + c8);
        }
        __syncthreads();
        half8 af[4][2], bf[2][2];
        #pragma unroll
        for (int s = 0; s < 4; s++)
            #pragma unroll
            for (int ks = 0; ks < 2; ks++)
                af[s][ks] = *(const half8*)(&As[s * 16 + lr][ks * 32 + lk * 8]);
        #pragma unroll
        for (int n = 0; n < 2; n++)
            #pragma unroll
            for (int ks = 0; ks < 2; ks++)
                bf[n][ks] = *(const half8*)(&Bs[(2 * w + n) * 16 + lr][ks * 32 + lk * 8]);
        #pragma unroll
        for (int s = 0; s < 4; s++) {
            #pragma unroll
            for (int n = 0; n < 2; n++) {
                acc[s][n] = __builtin_amdgcn_mfma_f32_16x16x32_f16(af[s][0], bf[n][0], acc[s][n], 0, 0, 0);
                acc[s][n] = __builtin_amdgcn_mfma_f32_16x16x32_f16(af[s][1], bf[n][1], acc[s][n], 0, 0, 0);
            }
        }
        __syncthreads();
    }
    #pragma unroll
    for (int s = 0; s < 4; s++) {
        int gr0 = row0 + s * 16 + lk * 4;
        #pragma unroll
        for (int n = 0; n < 2; n++) {
            int col = (2 * w + n) * 16 + lr;
            #pragma unroll
            for (int j = 0; j < 4; j++) {
                int gm = gr0 + j;
                if (gm < M) T[(size_t)gm * 128 + col] = (_Float16)acc[s][n][j];
            }
        }
    }
}

// ---------------- aggregation + bias + relu (wave per node, fp16 in/out) ----

__global__ __launch_bounds__(256) void agg_k(const __half2* __restrict__ Th, __half2* __restrict__ Hh,
                                             const int2* __restrict__ meta,
                                             const int* __restrict__ row_ptr, const int* __restrict__ cnt,
                                             const float* __restrict__ dinv, const float* __restrict__ bias,
                                             int n) {
    int wave = threadIdx.x >> 6, lane = threadIdx.x & 63;
    int d = blockIdx.x * 4 + wave;
    if (d >= n) return;
    float nd = dinv[d];
    float2 ts = __half22float2(Th[(size_t)d * 64 + lane]);
    float ax = nd * ts.x;
    float ay = nd * ts.y;
    int start = row_ptr[d];
    int c = cnt[d];
    int j = 0;
    for (; j + 1 < c; j += 2) {
        int2 m0 = meta[start + j];
        int2 m1 = meta[start + j + 1];
        float2 t0 = __half22float2(Th[(size_t)m0.x * 64 + lane]);
        float2 t1 = __half22float2(Th[(size_t)m1.x * 64 + lane]);
        float w0 = __int_as_float(m0.y);
        float w1 = __int_as_float(m1.y);
        ax = fmaf(w0, t0.x, ax);
        ay = fmaf(w0, t0.y, ay);
        ax = fmaf(w1, t1.x, ax);
        ay = fmaf(w1, t1.y, ay);
    }
    if (j < c) {
        int2 m0 = meta[start + j];
        float2 t0 = __half22float2(Th[(size_t)m0.x * 64 + lane]);
        float w0 = __int_as_float(m0.y);
        ax = fmaf(w0, t0.x, ax);
        ay = fmaf(w0, t0.y, ay);
    }
    float2 bb = *(const float2*)(bias + 2 * lane);
    float vx = fmaf(nd, ax, bb.x);
    float vy = fmaf(nd, ay, bb.y);
    vx = vx > 0.f ? vx : 0.f;
    vy = vy > 0.f ? vy : 0.f;
    Hh[(size_t)d * 64 + lane] = __floats2half2_rn(vx, vy);
}

// ---------------- final FC(128->10) + softmax (fp16 input) ----------------

__global__ __launch_bounds__(256) void fc_k(const __half2* __restrict__ Hh, const float* __restrict__ FW,
                                            const float* __restrict__ FB, float* __restrict__ out, int n) {
    __shared__ float fw[128 * 10];
    __shared__ float fb[16];
    int tid = threadIdx.x;
    for (int i = tid; i < 128 * 10; i += 256) fw[i] = FW[i];
    if (tid < 10) fb[tid] = FB[tid];
    __syncthreads();
    int wave = tid >> 6, lane = tid & 63;
    int r = blockIdx.x * 4 + wave;
    if (r >= n) return;
    float2 hv = __half22float2(Hh[(size_t)r * 64 + lane]);
    float p[10];
    #pragma unroll
    for (int c = 0; c < 10; c++)
        p[c] = hv.x * fw[(2 * lane) * 10 + c] + hv.y * fw[(2 * lane + 1) * 10 + c];
    #pragma unroll
    for (int off = 32; off > 0; off >>= 1) {
        #pragma unroll
        for (int c = 0; c < 10; c++) p[c] += __shfl_xor(p[c], off);
    }
    float m = -1e30f;
    #pragma unroll
    for (int c = 0; c < 10; c++) { p[c] += fb[c]; m = fmaxf(m, p[c]); }
    float s = 0.f;
    float e[10];
    #pragma unroll
    for (int c = 0; c < 10; c++) { e[c] = __expf(p[c] - m); s += e[c]; }
    float inv = 1.f / s;
    if (lane < 10) out[(size_t)r * 10 + lane] = e[lane] * inv;
}

// ---------------- host ----------------

extern "C" void kernel_launch(void* const* d_in, const int* in_sizes, int n_in,
                              void* d_out, int out_size, void* d_ws, size_t ws_size,
                              hipStream_t stream) {
    const float* x  = (const float*)d_in[0];
    const int*   ei = (const int*)d_in[1];
    const float* ew = (const float*)d_in[2];
    const float* W1 = (const float*)d_in[3];
    const float* b1 = (const float*)d_in[4];
    const float* W2 = (const float*)d_in[5];
    const float* b2 = (const float*)d_in[6];
    const float* W3 = (const float*)d_in[7];
    const float* b3 = (const float*)d_in[8];
    const float* FW = (const float*)d_in[9];
    const float* FB = (const float*)d_in[10];
    float* out = (float*)d_out;

    int Hd = in_sizes[4];            // 128
    int F  = in_sizes[3] / Hd;       // 256
    int N  = in_sizes[0] / F;        // 50000
    int E  = in_sizes[1] / 2;        // 800000

    const int* src = ei;
    const int* dst = ei + E;

    char* ws = (char*)d_ws;
    size_t off = 0;
    auto alloc = [&](size_t bytes) -> void* {
        void* p = ws + off;
        off = (off + bytes + 255) & ~(size_t)255;
        return p;
    };
    float*    dinv    = (float*)alloc((size_t)N * 4);
    int*      cnt     = (int*)alloc((size_t)N * 4);
    int*      row_ptr = (int*)alloc((size_t)N * 4);
    int*      rank    = (int*)alloc((size_t)E * 4);
    int*      bsum    = (int*)alloc(4096);
    int2*     meta    = (int2*)alloc((size_t)E * 8);
    _Float16* T       = (_Float16*)alloc((size_t)N * Hd * 2);
    // union region: xh [N][F] fp16 (dead after layer-1 GEMM) then Hh [N][Hd] fp16
    _Float16* xh      = (_Float16*)alloc((size_t)N * F * 2);
    _Float16* Hh      = xh;
    _Float16* WT1     = (_Float16*)alloc((size_t)(F + 2 * Hd) * Hd * 2);
    _Float16* WT2     = WT1 + (size_t)F * Hd;
    _Float16* WT3     = WT2 + (size_t)Hd * Hd;

    int nb = (N + 1023) / 1024;

    // converts
    int n4 = N * F / 4;
    cvtx_k<<<(n4 + 255) / 256, 256, 0, stream>>>((const float4*)x, (half4v*)xh, n4);
    int nw = (F + 2 * Hd) * Hd;
    cvtw_k<<<(nw + 255) / 256, 256, 0, stream>>>(W1, W2, W3, WT1, WT2, WT3, F, Hd);

    // CSR build
    hipMemsetAsync(cnt, 0, (size_t)N * 4, stream);
    rank_k<<<(E + 255) / 256, 256, 0, stream>>>(dst, cnt, rank, E);
    scan1_k<<<nb, 256, 0, stream>>>(cnt, bsum, N);
    scan2_k<<<1, 64, 0, stream>>>(bsum, nb);
    scan3_k<<<nb, 256, 0, stream>>>(cnt, bsum, row_ptr, N);
    fill_k<<<(E + 255) / 256, 256, 0, stream>>>(src, dst, ew, row_ptr, rank, meta, E);
    deg_k<<<(N + 255) / 256, 256, 0, stream>>>(meta, row_ptr, cnt, dinv, N);
    scale_k<<<(E + 255) / 256, 256, 0, stream>>>(meta, dinv, E);

    int gb = (N + 63) / 64;
    int ab = (N + 3) / 4;
    // layer 1
    gemmh_k<<<gb, 256, 0, stream>>>(xh, WT1, T, N, F);
    agg_k<<<ab, 256, 0, stream>>>((const __half2*)T, (__half2*)Hh, meta, row_ptr, cnt, dinv, b1, N);
    // layer 2
    gemmh_k<<<gb, 256, 0, stream>>>(Hh, WT2, T, N, Hd);
    agg_k<<<ab, 256, 0, stream>>>((const __half2*)T, (__half2*)Hh, meta, row_ptr, cnt, dinv, b2, N);
    // layer 3
    gemmh_k<<<gb, 256, 0, stream>>>(Hh, WT3, T, N, Hd);
    agg_k<<<ab, 256, 0, stream>>>((const __half2*)T, (__half2*)Hh, meta, row_ptr, cnt, dinv, b3, N);
    // FC + softmax
    fc_k<<<(N + 3) / 4, 256, 0, stream>>>((const __half2*)Hh, FW, FB, out, N);
}

// Round 10
// 385.030 us; speedup vs baseline: 1.4064x; 1.0933x over previous
//
#include <hip/hip_runtime.h>
#include <hip/hip_fp16.h>
#include <math.h>

typedef _Float16 half8 __attribute__((ext_vector_type(8)));
typedef _Float16 half4v __attribute__((ext_vector_type(4)));
typedef float float4v __attribute__((ext_vector_type(4)));

// ---------------- CSR build (single-atomic counting sort) ----------------

__global__ __launch_bounds__(256) void rank_k(const int* __restrict__ dst, int* cnt,
                                              int* __restrict__ rank, int E) {
    int e = blockIdx.x * 256 + threadIdx.x;
    if (e < E) {
        int d = dst[e];
        rank[e] = atomicAdd(&cnt[d], 1);
    }
}

__global__ __launch_bounds__(256) void scan1_k(const int* __restrict__ cnt, int* bsum, int n) {
    __shared__ int sdata[256];
    int base = blockIdx.x * 1024;
    int t = threadIdx.x;
    int s = 0;
    #pragma unroll
    for (int j = 0; j < 4; j++) {
        int i = base + t * 4 + j;
        if (i < n) s += cnt[i];
    }
    sdata[t] = s;
    __syncthreads();
    for (int off = 128; off > 0; off >>= 1) {
        if (t < off) sdata[t] += sdata[t + off];
        __syncthreads();
    }
    if (t == 0) bsum[blockIdx.x] = sdata[0];
}

__global__ void scan2_k(int* bsum, int nb) {
    if (threadIdx.x == 0 && blockIdx.x == 0) {
        int run = 0;
        for (int b = 0; b < nb; b++) { int v = bsum[b]; bsum[b] = run; run += v; }
    }
}

__global__ __launch_bounds__(256) void scan3_k(const int* __restrict__ cnt, const int* __restrict__ bsum,
                                               int* row_ptr, int n) {
    __shared__ int sdata[256];
    int base = blockIdx.x * 1024;
    int t = threadIdx.x;
    int loc[4];
    int s = 0;
    #pragma unroll
    for (int j = 0; j < 4; j++) {
        int i = base + t * 4 + j;
        loc[j] = (i < n) ? cnt[i] : 0;
        s += loc[j];
    }
    sdata[t] = s;
    __syncthreads();
    for (int off = 1; off < 256; off <<= 1) {
        int v = (t >= off) ? sdata[t - off] : 0;
        __syncthreads();
        sdata[t] += v;
        __syncthreads();
    }
    int excl = sdata[t] - s;
    int run = bsum[blockIdx.x] + excl;
    #pragma unroll
    for (int j = 0; j < 4; j++) {
        int i = base + t * 4 + j;
        if (i < n) row_ptr[i] = run;
        run += loc[j];
    }
}

__global__ __launch_bounds__(256) void fill_k(const int* __restrict__ src, const int* __restrict__ dst,
                                              const float* __restrict__ ew,
                                              const int* __restrict__ row_ptr,
                                              const int* __restrict__ rank,
                                              int2* __restrict__ meta, int E) {
    int e = blockIdx.x * 256 + threadIdx.x;
    if (e < E) {
        int d = dst[e];
        int pos = row_ptr[d] + rank[e];
        meta[pos] = make_int2(src[e], __float_as_int(ew[e]));
    }
}

__global__ __launch_bounds__(256) void deg_k(const int2* __restrict__ meta,
                                             const int* __restrict__ row_ptr,
                                             const int* __restrict__ cnt,
                                             float* __restrict__ dinv, int n) {
    int d = blockIdx.x * 256 + threadIdx.x;
    if (d < n) {
        int start = row_ptr[d];
        int c = cnt[d];
        float s = 1.0f;
        for (int j = 0; j < c; j++) s += __int_as_float(meta[start + j].y);
        dinv[d] = rsqrtf(s);
    }
}

__global__ __launch_bounds__(256) void scale_k(int2* __restrict__ meta,
                                               const float* __restrict__ dinv, int E) {
    int e = blockIdx.x * 256 + threadIdx.x;
    if (e < E) {
        int2 m = meta[e];
        float wn = __int_as_float(m.y) * dinv[m.x];
        ((int*)meta)[2 * e + 1] = __float_as_int(wn);
    }
}

// ---------------- converts ----------------

__global__ __launch_bounds__(256) void cvtx_k(const float4* __restrict__ in,
                                              half4v* __restrict__ out, int n4) {
    int i = blockIdx.x * 256 + threadIdx.x;
    if (i < n4) {
        float4 v = in[i];
        half4v o = {(_Float16)v.x, (_Float16)v.y, (_Float16)v.z, (_Float16)v.w};
        out[i] = o;
    }
}

// W[K][128] fp32 -> WT[128][K] fp16, all three weight matrices in one kernel
__global__ __launch_bounds__(256) void cvtw_k(const float* __restrict__ W1, const float* __restrict__ W2,
                                              const float* __restrict__ W3,
                                              _Float16* __restrict__ T1, _Float16* __restrict__ T2,
                                              _Float16* __restrict__ T3, int F, int Hd) {
    int i = blockIdx.x * 256 + threadIdx.x;
    int n1 = F * Hd, n2 = Hd * Hd;
    if (i < n1) {
        int k = i >> 7, n = i & 127;
        T1[n * F + k] = (_Float16)W1[i];
    } else if (i < n1 + n2) {
        int j = i - n1; int k = j >> 7, n = j & 127;
        T2[n * Hd + k] = (_Float16)W2[j];
    } else if (i < n1 + 2 * n2) {
        int j = i - n1 - n2; int k = j >> 7, n = j & 127;
        T3[n * Hd + k] = (_Float16)W3[j];
    }
}

// ---------------- MFMA fp16 GEMM: T[M,128] = A[M,K] @ BT[128,K]^T ----------
// 256 threads = 4 waves. BM=64 (4 stripes of 16), BK=64.
// Wave w owns N-tiles {2w, 2w+1} across all 4 M-stripes.
// mfma_f32_16x16x32_f16; A/B use the same per-lane k mapping so any
// k-permutation cancels. C/D: col=lane&15, row=(lane>>4)*4+reg (HW-verified).

__global__ __launch_bounds__(256) void gemmh_k(const _Float16* __restrict__ A,
                                               const _Float16* __restrict__ BT,
                                               _Float16* __restrict__ T, int M, int K) {
    __shared__ __align__(16) _Float16 As[64][72];    // +8 pad: 144B row stride
    __shared__ __align__(16) _Float16 Bs[128][72];
    int tid = threadIdx.x;
    int w = tid >> 6, l = tid & 63;
    int lr = l & 15, lk = l >> 4;
    int row0 = blockIdx.x * 64;
    float4v acc[4][2];
    #pragma unroll
    for (int s = 0; s < 4; s++)
        #pragma unroll
        for (int n = 0; n < 2; n++)
            acc[s][n] = (float4v){0.f, 0.f, 0.f, 0.f};

    for (int k0 = 0; k0 < K; k0 += 64) {
        // stage A tile 64x64 halves: 512 chunks of 8 (8 chunks per row)
        #pragma unroll
        for (int j = 0; j < 2; j++) {
            int idx = tid + j * 256;          // 0..511
            int r = idx >> 3;                 // 0..63
            int c8 = (idx & 7) * 8;           // 0..56
            int gm = row0 + r;
            half8 v = {0, 0, 0, 0, 0, 0, 0, 0};
            if (gm < M) v = *(const half8*)(A + (size_t)gm * K + k0 + c8);
            *(half8*)(&As[r][c8]) = v;
        }
        // stage B tile 128x64 halves: 1024 chunks of 8
        #pragma unroll
        for (int j = 0; j < 4; j++) {
            int idx = tid + j * 256;          // 0..1023
            int r = idx >> 3;                 // 0..127
            int c8 = (idx & 7) * 8;
            *(half8*)(&Bs[r][c8]) = *(const half8*)(BT + (size_t)r * K + k0 + c8);
        }
        __syncthreads();
        half8 af[4][2], bf[2][2];
        #pragma unroll
        for (int s = 0; s < 4; s++)
            #pragma unroll
            for (int ks = 0; ks < 2; ks++)
                af[s][ks] = *(const half8*)(&As[s * 16 + lr][ks * 32 + lk * 8]);
        #pragma unroll
        for (int n = 0; n < 2; n++)
            #pragma unroll
            for (int ks = 0; ks < 2; ks++)
                bf[n][ks] = *(const half8*)(&Bs[(2 * w + n) * 16 + lr][ks * 32 + lk * 8]);
        #pragma unroll
        for (int s = 0; s < 4; s++) {
            #pragma unroll
            for (int n = 0; n < 2; n++) {
                acc[s][n] = __builtin_amdgcn_mfma_f32_16x16x32_f16(af[s][0], bf[n][0], acc[s][n], 0, 0, 0);
                acc[s][n] = __builtin_amdgcn_mfma_f32_16x16x32_f16(af[s][1], bf[n][1], acc[s][n], 0, 0, 0);
            }
        }
        __syncthreads();
    }
    #pragma unroll
    for (int s = 0; s < 4; s++) {
        int gr0 = row0 + s * 16 + lk * 4;
        #pragma unroll
        for (int n = 0; n < 2; n++) {
            int col = (2 * w + n) * 16 + lr;
            #pragma unroll
            for (int j = 0; j < 4; j++) {
                int gm = gr0 + j;
                if (gm < M) T[(size_t)gm * 128 + col] = (_Float16)acc[s][n][j];
            }
        }
    }
}

// ---------------- aggregation + bias + relu (wave per node, fp16 in/out) ----
// 4-deep gather pipeline: meta for batch i+1 prefetched before batch i's
// gathers are consumed -> 4 independent gathers in flight per wave.

__global__ __launch_bounds__(256) void agg_k(const __half2* __restrict__ Th, __half2* __restrict__ Hh,
                                             const int2* __restrict__ meta,
                                             const int* __restrict__ row_ptr, const int* __restrict__ cnt,
                                             const float* __restrict__ dinv, const float* __restrict__ bias,
                                             int n) {
    int wave = threadIdx.x >> 6, lane = threadIdx.x & 63;
    int d = blockIdx.x * 4 + wave;
    if (d >= n) return;
    float nd = dinv[d];
    float2 ts = __half22float2(Th[(size_t)d * 64 + lane]);
    float ax = nd * ts.x;
    float ay = nd * ts.y;
    int start = row_ptr[d];
    int c = cnt[d];
    int j = 0;
    if (c >= 8) {
        int2 m0 = meta[start + 0];
        int2 m1 = meta[start + 1];
        int2 m2 = meta[start + 2];
        int2 m3 = meta[start + 3];
        for (; j + 8 <= c; j += 4) {
            int2 n0 = meta[start + j + 4];
            int2 n1 = meta[start + j + 5];
            int2 n2 = meta[start + j + 6];
            int2 n3 = meta[start + j + 7];
            float2 t0 = __half22float2(Th[(size_t)m0.x * 64 + lane]);
            float2 t1 = __half22float2(Th[(size_t)m1.x * 64 + lane]);
            float2 t2 = __half22float2(Th[(size_t)m2.x * 64 + lane]);
            float2 t3 = __half22float2(Th[(size_t)m3.x * 64 + lane]);
            float w0 = __int_as_float(m0.y);
            float w1 = __int_as_float(m1.y);
            float w2 = __int_as_float(m2.y);
            float w3 = __int_as_float(m3.y);
            ax = fmaf(w0, t0.x, ax); ay = fmaf(w0, t0.y, ay);
            ax = fmaf(w1, t1.x, ax); ay = fmaf(w1, t1.y, ay);
            ax = fmaf(w2, t2.x, ax); ay = fmaf(w2, t2.y, ay);
            ax = fmaf(w3, t3.x, ax); ay = fmaf(w3, t3.y, ay);
            m0 = n0; m1 = n1; m2 = n2; m3 = n3;
        }
        // drain the preloaded batch
        {
            float2 t0 = __half22float2(Th[(size_t)m0.x * 64 + lane]);
            float2 t1 = __half22float2(Th[(size_t)m1.x * 64 + lane]);
            float2 t2 = __half22float2(Th[(size_t)m2.x * 64 + lane]);
            float2 t3 = __half22float2(Th[(size_t)m3.x * 64 + lane]);
            float w0 = __int_as_float(m0.y);
            float w1 = __int_as_float(m1.y);
            float w2 = __int_as_float(m2.y);
            float w3 = __int_as_float(m3.y);
            ax = fmaf(w0, t0.x, ax); ay = fmaf(w0, t0.y, ay);
            ax = fmaf(w1, t1.x, ax); ay = fmaf(w1, t1.y, ay);
            ax = fmaf(w2, t2.x, ax); ay = fmaf(w2, t2.y, ay);
            ax = fmaf(w3, t3.x, ax); ay = fmaf(w3, t3.y, ay);
            j += 4;
        }
    }
    for (; j < c; j++) {
        int2 m0 = meta[start + j];
        float2 t0 = __half22float2(Th[(size_t)m0.x * 64 + lane]);
        float w0 = __int_as_float(m0.y);
        ax = fmaf(w0, t0.x, ax);
        ay = fmaf(w0, t0.y, ay);
    }
    float2 bb = *(const float2*)(bias + 2 * lane);
    float vx = fmaf(nd, ax, bb.x);
    float vy = fmaf(nd, ay, bb.y);
    vx = vx > 0.f ? vx : 0.f;
    vy = vy > 0.f ? vy : 0.f;
    Hh[(size_t)d * 64 + lane] = __floats2half2_rn(vx, vy);
}

// ---------------- final FC(128->10) + softmax (fp16 input) ----------------

__global__ __launch_bounds__(256) void fc_k(const __half2* __restrict__ Hh, const float* __restrict__ FW,
                                            const float* __restrict__ FB, float* __restrict__ out, int n) {
    __shared__ float fw[128 * 10];
    __shared__ float fb[16];
    int tid = threadIdx.x;
    for (int i = tid; i < 128 * 10; i += 256) fw[i] = FW[i];
    if (tid < 10) fb[tid] = FB[tid];
    __syncthreads();
    int wave = tid >> 6, lane = tid & 63;
    int r = blockIdx.x * 4 + wave;
    if (r >= n) return;
    float2 hv = __half22float2(Hh[(size_t)r * 64 + lane]);
    float p[10];
    #pragma unroll
    for (int c = 0; c < 10; c++)
        p[c] = hv.x * fw[(2 * lane) * 10 + c] + hv.y * fw[(2 * lane + 1) * 10 + c];
    #pragma unroll
    for (int off = 32; off > 0; off >>= 1) {
        #pragma unroll
        for (int c = 0; c < 10; c++) p[c] += __shfl_xor(p[c], off);
    }
    float m = -1e30f;
    #pragma unroll
    for (int c = 0; c < 10; c++) { p[c] += fb[c]; m = fmaxf(m, p[c]); }
    float s = 0.f;
    float e[10];
    #pragma unroll
    for (int c = 0; c < 10; c++) { e[c] = __expf(p[c] - m); s += e[c]; }
    float inv = 1.f / s;
    if (lane < 10) out[(size_t)r * 10 + lane] = e[lane] * inv;
}

// ---------------- host ----------------

extern "C" void kernel_launch(void* const* d_in, const int* in_sizes, int n_in,
                              void* d_out, int out_size, void* d_ws, size_t ws_size,
                              hipStream_t stream) {
    const float* x  = (const float*)d_in[0];
    const int*   ei = (const int*)d_in[1];
    const float* ew = (const float*)d_in[2];
    const float* W1 = (const float*)d_in[3];
    const float* b1 = (const float*)d_in[4];
    const float* W2 = (const float*)d_in[5];
    const float* b2 = (const float*)d_in[6];
    const float* W3 = (const float*)d_in[7];
    const float* b3 = (const float*)d_in[8];
    const float* FW = (const float*)d_in[9];
    const float* FB = (const float*)d_in[10];
    float* out = (float*)d_out;

    int Hd = in_sizes[4];            // 128
    int F  = in_sizes[3] / Hd;       // 256
    int N  = in_sizes[0] / F;        // 50000
    int E  = in_sizes[1] / 2;        // 800000

    const int* src = ei;
    const int* dst = ei + E;

    char* ws = (char*)d_ws;
    size_t off = 0;
    auto alloc = [&](size_t bytes) -> void* {
        void* p = ws + off;
        off = (off + bytes + 255) & ~(size_t)255;
        return p;
    };
    float*    dinv    = (float*)alloc((size_t)N * 4);
    int*      cnt     = (int*)alloc((size_t)N * 4);
    int*      row_ptr = (int*)alloc((size_t)N * 4);
    int*      rank    = (int*)alloc((size_t)E * 4);
    int*      bsum    = (int*)alloc(4096);
    int2*     meta    = (int2*)alloc((size_t)E * 8);
    _Float16* T       = (_Float16*)alloc((size_t)N * Hd * 2);
    // union region: xh [N][F] fp16 (dead after layer-1 GEMM) then Hh [N][Hd] fp16
    _Float16* xh      = (_Float16*)alloc((size_t)N * F * 2);
    _Float16* Hh      = xh;
    _Float16* WT1     = (_Float16*)alloc((size_t)(F + 2 * Hd) * Hd * 2);
    _Float16* WT2     = WT1 + (size_t)F * Hd;
    _Float16* WT3     = WT2 + (size_t)Hd * Hd;

    int nb = (N + 1023) / 1024;

    // converts
    int n4 = N * F / 4;
    cvtx_k<<<(n4 + 255) / 256, 256, 0, stream>>>((const float4*)x, (half4v*)xh, n4);
    int nw = (F + 2 * Hd) * Hd;
    cvtw_k<<<(nw + 255) / 256, 256, 0, stream>>>(W1, W2, W3, WT1, WT2, WT3, F, Hd);

    // CSR build
    hipMemsetAsync(cnt, 0, (size_t)N * 4, stream);
    rank_k<<<(E + 255) / 256, 256, 0, stream>>>(dst, cnt, rank, E);
    scan1_k<<<nb, 256, 0, stream>>>(cnt, bsum, N);
    scan2_k<<<1, 64, 0, stream>>>(bsum, nb);
    scan3_k<<<nb, 256, 0, stream>>>(cnt, bsum, row_ptr, N);
    fill_k<<<(E + 255) / 256, 256, 0, stream>>>(src, dst, ew, row_ptr, rank, meta, E);
    deg_k<<<(N + 255) / 256, 256, 0, stream>>>(meta, row_ptr, cnt, dinv, N);
    scale_k<<<(E + 255) / 256, 256, 0, stream>>>(meta, dinv, E);

    int gb = (N + 63) / 64;
    int ab = (N + 3) / 4;
    // layer 1
    gemmh_k<<<gb, 256, 0, stream>>>(xh, WT1, T, N, F);
    agg_k<<<ab, 256, 0, stream>>>((const __half2*)T, (__half2*)Hh, meta, row_ptr, cnt, dinv, b1, N);
    // layer 2
    gemmh_k<<<gb, 256, 0, stream>>>(Hh, WT2, T, N, Hd);
    agg_k<<<ab, 256, 0, stream>>>((const __half2*)T, (__half2*)Hh, meta, row_ptr, cnt, dinv, b2, N);
    // layer 3
    gemmh_k<<<gb, 256, 0, stream>>>(Hh, WT3, T, N, Hd);
    agg_k<<<ab, 256, 0, stream>>>((const __half2*)T, (__half2*)Hh, meta, row_ptr, cnt, dinv, b3, N);
    // FC + softmax
    fc_k<<<(N + 3) / 4, 256, 0, stream>>>((const __half2*)Hh, FW, FB, out, N);
}

// Round 11
// 347.183 us; speedup vs baseline: 1.5598x; 1.1090x over previous
//
#include <hip/hip_runtime.h>
#include <hip/hip_fp16.h>
#include <math.h>

typedef _Float16 half8 __attribute__((ext_vector_type(8)));
typedef _Float16 half4v __attribute__((ext_vector_type(4)));
typedef float float4v __attribute__((ext_vector_type(4)));

// ---------------- CSR build (single-atomic counting sort) ----------------

__global__ __launch_bounds__(256) void rank_k(const int* __restrict__ dst, int* cnt,
                                              int* __restrict__ rank, int E) {
    int e = blockIdx.x * 256 + threadIdx.x;
    if (e < E) {
        int d = dst[e];
        rank[e] = atomicAdd(&cnt[d], 1);
    }
}

__global__ __launch_bounds__(256) void scan1_k(const int* __restrict__ cnt, int* bsum, int n) {
    __shared__ int sdata[256];
    int base = blockIdx.x * 1024;
    int t = threadIdx.x;
    int s = 0;
    #pragma unroll
    for (int j = 0; j < 4; j++) {
        int i = base + t * 4 + j;
        if (i < n) s += cnt[i];
    }
    sdata[t] = s;
    __syncthreads();
    for (int off = 128; off > 0; off >>= 1) {
        if (t < off) sdata[t] += sdata[t + off];
        __syncthreads();
    }
    if (t == 0) bsum[blockIdx.x] = sdata[0];
}

__global__ void scan2_k(int* bsum, int nb) {
    if (threadIdx.x == 0 && blockIdx.x == 0) {
        int run = 0;
        for (int b = 0; b < nb; b++) { int v = bsum[b]; bsum[b] = run; run += v; }
    }
}

__global__ __launch_bounds__(256) void scan3_k(const int* __restrict__ cnt, const int* __restrict__ bsum,
                                               int* row_ptr, int n) {
    __shared__ int sdata[256];
    int base = blockIdx.x * 1024;
    int t = threadIdx.x;
    int loc[4];
    int s = 0;
    #pragma unroll
    for (int j = 0; j < 4; j++) {
        int i = base + t * 4 + j;
        loc[j] = (i < n) ? cnt[i] : 0;
        s += loc[j];
    }
    sdata[t] = s;
    __syncthreads();
    for (int off = 1; off < 256; off <<= 1) {
        int v = (t >= off) ? sdata[t - off] : 0;
        __syncthreads();
        sdata[t] += v;
        __syncthreads();
    }
    int excl = sdata[t] - s;
    int run = bsum[blockIdx.x] + excl;
    #pragma unroll
    for (int j = 0; j < 4; j++) {
        int i = base + t * 4 + j;
        if (i < n) row_ptr[i] = run;
        run += loc[j];
    }
}

__global__ __launch_bounds__(256) void fill_k(const int* __restrict__ src, const int* __restrict__ dst,
                                              const float* __restrict__ ew,
                                              const int* __restrict__ row_ptr,
                                              const int* __restrict__ rank,
                                              int2* __restrict__ meta, int E) {
    int e = blockIdx.x * 256 + threadIdx.x;
    if (e < E) {
        int d = dst[e];
        int pos = row_ptr[d] + rank[e];
        meta[pos] = make_int2(src[e], __float_as_int(ew[e]));
    }
}

__global__ __launch_bounds__(256) void deg_k(const int2* __restrict__ meta,
                                             const int* __restrict__ row_ptr,
                                             const int* __restrict__ cnt,
                                             float* __restrict__ dinv, int n) {
    int d = blockIdx.x * 256 + threadIdx.x;
    if (d < n) {
        int start = row_ptr[d];
        int c = cnt[d];
        float s = 1.0f;
        for (int j = 0; j < c; j++) s += __int_as_float(meta[start + j].y);
        dinv[d] = rsqrtf(s);
    }
}

__global__ __launch_bounds__(256) void scale_k(int2* __restrict__ meta,
                                               const float* __restrict__ dinv, int E) {
    int e = blockIdx.x * 256 + threadIdx.x;
    if (e < E) {
        int2 m = meta[e];
        float wn = __int_as_float(m.y) * dinv[m.x];
        ((int*)meta)[2 * e + 1] = __float_as_int(wn);
    }
}

// ---------------- converts ----------------

__global__ __launch_bounds__(256) void cvtx_k(const float4* __restrict__ in,
                                              half4v* __restrict__ out, int n4) {
    int i = blockIdx.x * 256 + threadIdx.x;
    if (i < n4) {
        float4 v = in[i];
        half4v o = {(_Float16)v.x, (_Float16)v.y, (_Float16)v.z, (_Float16)v.w};
        out[i] = o;
    }
}

// W[K][128] fp32 -> WT[128][K] fp16 (x3), plus FW[128][10] -> fwh[16][128] fp16
__global__ __launch_bounds__(256) void cvtw_k(const float* __restrict__ W1, const float* __restrict__ W2,
                                              const float* __restrict__ W3, const float* __restrict__ FW,
                                              _Float16* __restrict__ T1, _Float16* __restrict__ T2,
                                              _Float16* __restrict__ T3, _Float16* __restrict__ fwh,
                                              int F, int Hd) {
    int i = blockIdx.x * 256 + threadIdx.x;
    int n1 = F * Hd, n2 = Hd * Hd;
    if (i < n1) {
        int k = i >> 7, n = i & 127;
        T1[n * F + k] = (_Float16)W1[i];
    } else if (i < n1 + n2) {
        int j = i - n1; int k = j >> 7, n = j & 127;
        T2[n * Hd + k] = (_Float16)W2[j];
    } else if (i < n1 + 2 * n2) {
        int j = i - n1 - n2; int k = j >> 7, n = j & 127;
        T3[n * Hd + k] = (_Float16)W3[j];
    } else if (i < n1 + 2 * n2 + 16 * 128) {
        int j = i - n1 - 2 * n2;           // j = c*128 + f
        int c = j >> 7, f = j & 127;
        fwh[j] = (c < 10) ? (_Float16)FW[f * 10 + c] : (_Float16)0.0f;
    }
}

// ---------------- MFMA fp16 GEMM: T[M,128] = A[M,K] @ BT[128,K]^T ----------
// 256 threads = 4 waves. BM=64 (4 stripes of 16), BK=64.
// Wave w owns N-tiles {2w, 2w+1} across all 4 M-stripes.
// mfma_f32_16x16x32_f16; A/B use the same per-lane k mapping so any
// k-permutation cancels. C/D: col=lane&15, row=(lane>>4)*4+reg (HW-verified).

__global__ __launch_bounds__(256) void gemmh_k(const _Float16* __restrict__ A,
                                               const _Float16* __restrict__ BT,
                                               _Float16* __restrict__ T, int M, int K) {
    __shared__ __align__(16) _Float16 As[64][72];    // +8 pad: 144B row stride
    __shared__ __align__(16) _Float16 Bs[128][72];
    int tid = threadIdx.x;
    int w = tid >> 6, l = tid & 63;
    int lr = l & 15, lk = l >> 4;
    int row0 = blockIdx.x * 64;
    float4v acc[4][2];
    #pragma unroll
    for (int s = 0; s < 4; s++)
        #pragma unroll
        for (int n = 0; n < 2; n++)
            acc[s][n] = (float4v){0.f, 0.f, 0.f, 0.f};

    for (int k0 = 0; k0 < K; k0 += 64) {
        // stage A tile 64x64 halves: 512 chunks of 8 (8 chunks per row)
        #pragma unroll
        for (int j = 0; j < 2; j++) {
            int idx = tid + j * 256;          // 0..511
            int r = idx >> 3;                 // 0..63
            int c8 = (idx & 7) * 8;           // 0..56
            int gm = row0 + r;
            half8 v = {0, 0, 0, 0, 0, 0, 0, 0};
            if (gm < M) v = *(const half8*)(A + (size_t)gm * K + k0 + c8);
            *(half8*)(&As[r][c8]) = v;
        }
        // stage B tile 128x64 halves: 1024 chunks of 8
        #pragma unroll
        for (int j = 0; j < 4; j++) {
            int idx = tid + j * 256;          // 0..1023
            int r = idx >> 3;                 // 0..127
            int c8 = (idx & 7) * 8;
            *(half8*)(&Bs[r][c8]) = *(const half8*)(BT + (size_t)r * K + k0 + c8);
        }
        __syncthreads();
        half8 af[4][2], bf[2][2];
        #pragma unroll
        for (int s = 0; s < 4; s++)
            #pragma unroll
            for (int ks = 0; ks < 2; ks++)
                af[s][ks] = *(const half8*)(&As[s * 16 + lr][ks * 32 + lk * 8]);
        #pragma unroll
        for (int n = 0; n < 2; n++)
            #pragma unroll
            for (int ks = 0; ks < 2; ks++)
                bf[n][ks] = *(const half8*)(&Bs[(2 * w + n) * 16 + lr][ks * 32 + lk * 8]);
        #pragma unroll
        for (int s = 0; s < 4; s++) {
            #pragma unroll
            for (int n = 0; n < 2; n++) {
                acc[s][n] = __builtin_amdgcn_mfma_f32_16x16x32_f16(af[s][0], bf[n][0], acc[s][n], 0, 0, 0);
                acc[s][n] = __builtin_amdgcn_mfma_f32_16x16x32_f16(af[s][1], bf[n][1], acc[s][n], 0, 0, 0);
            }
        }
        __syncthreads();
    }
    #pragma unroll
    for (int s = 0; s < 4; s++) {
        int gr0 = row0 + s * 16 + lk * 4;
        #pragma unroll
        for (int n = 0; n < 2; n++) {
            int col = (2 * w + n) * 16 + lr;
            #pragma unroll
            for (int j = 0; j < 4; j++) {
                int gm = gr0 + j;
                if (gm < M) T[(size_t)gm * 128 + col] = (_Float16)acc[s][n][j];
            }
        }
    }
}

// ---------------- aggregation + bias + relu (wave per node, fp16 in/out) ----
// 4-deep gather pipeline: meta for batch i+1 prefetched before batch i's
// gathers are consumed -> 4 independent gathers in flight per wave.

__global__ __launch_bounds__(256) void agg_k(const __half2* __restrict__ Th, __half2* __restrict__ Hh,
                                             const int2* __restrict__ meta,
                                             const int* __restrict__ row_ptr, const int* __restrict__ cnt,
                                             const float* __restrict__ dinv, const float* __restrict__ bias,
                                             int n) {
    int wave = threadIdx.x >> 6, lane = threadIdx.x & 63;
    int d = blockIdx.x * 4 + wave;
    if (d >= n) return;
    float nd = dinv[d];
    float2 ts = __half22float2(Th[(size_t)d * 64 + lane]);
    float ax = nd * ts.x;
    float ay = nd * ts.y;
    int start = row_ptr[d];
    int c = cnt[d];
    int j = 0;
    if (c >= 8) {
        int2 m0 = meta[start + 0];
        int2 m1 = meta[start + 1];
        int2 m2 = meta[start + 2];
        int2 m3 = meta[start + 3];
        for (; j + 8 <= c; j += 4) {
            int2 n0 = meta[start + j + 4];
            int2 n1 = meta[start + j + 5];
            int2 n2 = meta[start + j + 6];
            int2 n3 = meta[start + j + 7];
            float2 t0 = __half22float2(Th[(size_t)m0.x * 64 + lane]);
            float2 t1 = __half22float2(Th[(size_t)m1.x * 64 + lane]);
            float2 t2 = __half22float2(Th[(size_t)m2.x * 64 + lane]);
            float2 t3 = __half22float2(Th[(size_t)m3.x * 64 + lane]);
            float w0 = __int_as_float(m0.y);
            float w1 = __int_as_float(m1.y);
            float w2 = __int_as_float(m2.y);
            float w3 = __int_as_float(m3.y);
            ax = fmaf(w0, t0.x, ax); ay = fmaf(w0, t0.y, ay);
            ax = fmaf(w1, t1.x, ax); ay = fmaf(w1, t1.y, ay);
            ax = fmaf(w2, t2.x, ax); ay = fmaf(w2, t2.y, ay);
            ax = fmaf(w3, t3.x, ax); ay = fmaf(w3, t3.y, ay);
            m0 = n0; m1 = n1; m2 = n2; m3 = n3;
        }
        // drain the preloaded batch
        {
            float2 t0 = __half22float2(Th[(size_t)m0.x * 64 + lane]);
            float2 t1 = __half22float2(Th[(size_t)m1.x * 64 + lane]);
            float2 t2 = __half22float2(Th[(size_t)m2.x * 64 + lane]);
            float2 t3 = __half22float2(Th[(size_t)m3.x * 64 + lane]);
            float w0 = __int_as_float(m0.y);
            float w1 = __int_as_float(m1.y);
            float w2 = __int_as_float(m2.y);
            float w3 = __int_as_float(m3.y);
            ax = fmaf(w0, t0.x, ax); ay = fmaf(w0, t0.y, ay);
            ax = fmaf(w1, t1.x, ax); ay = fmaf(w1, t1.y, ay);
            ax = fmaf(w2, t2.x, ax); ay = fmaf(w2, t2.y, ay);
            ax = fmaf(w3, t3.x, ax); ay = fmaf(w3, t3.y, ay);
            j += 4;
        }
    }
    for (; j < c; j++) {
        int2 m0 = meta[start + j];
        float2 t0 = __half22float2(Th[(size_t)m0.x * 64 + lane]);
        float w0 = __int_as_float(m0.y);
        ax = fmaf(w0, t0.x, ax);
        ay = fmaf(w0, t0.y, ay);
    }
    float2 bb = *(const float2*)(bias + 2 * lane);
    float vx = fmaf(nd, ax, bb.x);
    float vy = fmaf(nd, ay, bb.y);
    vx = vx > 0.f ? vx : 0.f;
    vy = vy > 0.f ? vy : 0.f;
    Hh[(size_t)d * 64 + lane] = __floats2half2_rn(vx, vy);
}

// ---------------- final FC(128->10) + softmax: MFMA 64x16 per block --------
// Same fragment addressing as gemmh_k (proven): af from Hs[stripe*16+lr],
// bf from Bs[lr], C at (row=lk*4+j, col=lr). Softmax reduces across the
// 16-lane lr-group via shfl_xor {1,2,4,8}; cols >=10 masked to -inf.

__global__ __launch_bounds__(256) void fc_k(const _Float16* __restrict__ Hh,
                                            const _Float16* __restrict__ fwh,
                                            const float* __restrict__ FB,
                                            float* __restrict__ out, int n) {
    __shared__ __align__(16) _Float16 Hs[64][136];   // 64 rows x 128, +8 pad
    __shared__ __align__(16) _Float16 Bs[16][136];   // fwh staged
    __shared__ float fbs[16];
    int tid = threadIdx.x;
    int r0 = blockIdx.x * 64;
    // stage H tile 64x128: 1024 chunks of 8
    #pragma unroll
    for (int j = 0; j < 4; j++) {
        int idx = tid + j * 256;
        int r = idx >> 4;                 // 16 chunks per row
        int c8 = (idx & 15) * 8;
        int gm = r0 + r;
        half8 v = {0, 0, 0, 0, 0, 0, 0, 0};
        if (gm < n) v = *(const half8*)(Hh + (size_t)gm * 128 + c8);
        *(half8*)(&Hs[r][c8]) = v;
    }
    // stage fwh 16x128: 256 chunks of 8
    {
        int r = tid >> 4;
        int c8 = (tid & 15) * 8;
        *(half8*)(&Bs[r][c8]) = *(const half8*)(fwh + r * 128 + c8);
    }
    if (tid < 16) fbs[tid] = (tid < 10) ? FB[tid] : 0.f;
    __syncthreads();

    int w = tid >> 6, l = tid & 63;
    int lr = l & 15, lk = l >> 4;
    half8 af[4], bf[4];
    #pragma unroll
    for (int ks = 0; ks < 4; ks++) {
        af[ks] = *(const half8*)(&Hs[w * 16 + lr][ks * 32 + lk * 8]);
        bf[ks] = *(const half8*)(&Bs[lr][ks * 32 + lk * 8]);
    }
    float4v acc = (float4v){0.f, 0.f, 0.f, 0.f};
    #pragma unroll
    for (int ks = 0; ks < 4; ks++)
        acc = __builtin_amdgcn_mfma_f32_16x16x32_f16(af[ks], bf[ks], acc, 0, 0, 0);

    float fbv = fbs[lr];
    float v[4], mx[4], e[4], sm[4];
    #pragma unroll
    for (int j = 0; j < 4; j++) v[j] = (lr < 10) ? acc[j] + fbv : -1e30f;
    #pragma unroll
    for (int j = 0; j < 4; j++) mx[j] = v[j];
    #pragma unroll
    for (int off = 1; off < 16; off <<= 1) {
        #pragma unroll
        for (int j = 0; j < 4; j++) mx[j] = fmaxf(mx[j], __shfl_xor(mx[j], off));
    }
    #pragma unroll
    for (int j = 0; j < 4; j++) e[j] = __expf(v[j] - mx[j]);
    #pragma unroll
    for (int j = 0; j < 4; j++) sm[j] = e[j];
    #pragma unroll
    for (int off = 1; off < 16; off <<= 1) {
        #pragma unroll
        for (int j = 0; j < 4; j++) sm[j] += __shfl_xor(sm[j], off);
    }
    if (lr < 10) {
        #pragma unroll
        for (int j = 0; j < 4; j++) {
            int gm = r0 + w * 16 + lk * 4 + j;
            if (gm < n) out[(size_t)gm * 10 + lr] = e[j] / sm[j];
        }
    }
}

// ---------------- host ----------------

extern "C" void kernel_launch(void* const* d_in, const int* in_sizes, int n_in,
                              void* d_out, int out_size, void* d_ws, size_t ws_size,
                              hipStream_t stream) {
    const float* x  = (const float*)d_in[0];
    const int*   ei = (const int*)d_in[1];
    const float* ew = (const float*)d_in[2];
    const float* W1 = (const float*)d_in[3];
    const float* b1 = (const float*)d_in[4];
    const float* W2 = (const float*)d_in[5];
    const float* b2 = (const float*)d_in[6];
    const float* W3 = (const float*)d_in[7];
    const float* b3 = (const float*)d_in[8];
    const float* FW = (const float*)d_in[9];
    const float* FB = (const float*)d_in[10];
    float* out = (float*)d_out;

    int Hd = in_sizes[4];            // 128
    int F  = in_sizes[3] / Hd;       // 256
    int N  = in_sizes[0] / F;        // 50000
    int E  = in_sizes[1] / 2;        // 800000

    const int* src = ei;
    const int* dst = ei + E;

    char* ws = (char*)d_ws;
    size_t off = 0;
    auto alloc = [&](size_t bytes) -> void* {
        void* p = ws + off;
        off = (off + bytes + 255) & ~(size_t)255;
        return p;
    };
    float*    dinv    = (float*)alloc((size_t)N * 4);
    int*      cnt     = (int*)alloc((size_t)N * 4);
    int*      row_ptr = (int*)alloc((size_t)N * 4);
    int*      rank    = (int*)alloc((size_t)E * 4);
    int*      bsum    = (int*)alloc(4096);
    int2*     meta    = (int2*)alloc((size_t)E * 8);
    _Float16* T       = (_Float16*)alloc((size_t)N * Hd * 2);
    // union region: xh [N][F] fp16 (dead after layer-1 GEMM) then Hh [N][Hd] fp16
    _Float16* xh      = (_Float16*)alloc((size_t)N * F * 2);
    _Float16* Hh      = xh;
    _Float16* WT1     = (_Float16*)alloc(((size_t)(F + 2 * Hd) * Hd + 16 * 128) * 2);
    _Float16* WT2     = WT1 + (size_t)F * Hd;
    _Float16* WT3     = WT2 + (size_t)Hd * Hd;
    _Float16* fwh     = WT3 + (size_t)Hd * Hd;

    int nb = (N + 1023) / 1024;

    // converts
    int n4 = N * F / 4;
    cvtx_k<<<(n4 + 255) / 256, 256, 0, stream>>>((const float4*)x, (half4v*)xh, n4);
    int nw = (F + 2 * Hd) * Hd + 16 * 128;
    cvtw_k<<<(nw + 255) / 256, 256, 0, stream>>>(W1, W2, W3, FW, WT1, WT2, WT3, fwh, F, Hd);

    // CSR build
    hipMemsetAsync(cnt, 0, (size_t)N * 4, stream);
    rank_k<<<(E + 255) / 256, 256, 0, stream>>>(dst, cnt, rank, E);
    scan1_k<<<nb, 256, 0, stream>>>(cnt, bsum, N);
    scan2_k<<<1, 64, 0, stream>>>(bsum, nb);
    scan3_k<<<nb, 256, 0, stream>>>(cnt, bsum, row_ptr, N);
    fill_k<<<(E + 255) / 256, 256, 0, stream>>>(src, dst, ew, row_ptr, rank, meta, E);
    deg_k<<<(N + 255) / 256, 256, 0, stream>>>(meta, row_ptr, cnt, dinv, N);
    scale_k<<<(E + 255) / 256, 256, 0, stream>>>(meta, dinv, E);

    int gb = (N + 63) / 64;
    int ab = (N + 3) / 4;
    // layer 1
    gemmh_k<<<gb, 256, 0, stream>>>(xh, WT1, T, N, F);
    agg_k<<<ab, 256, 0, stream>>>((const __half2*)T, (__half2*)Hh, meta, row_ptr, cnt, dinv, b1, N);
    // layer 2
    gemmh_k<<<gb, 256, 0, stream>>>(Hh, WT2, T, N, Hd);
    agg_k<<<ab, 256, 0, stream>>>((const __half2*)T, (__half2*)Hh, meta, row_ptr, cnt, dinv, b2, N);
    // layer 3
    gemmh_k<<<gb, 256, 0, stream>>>(Hh, WT3, T, N, Hd);
    agg_k<<<ab, 256, 0, stream>>>((const __half2*)T, (__half2*)Hh, meta, row_ptr, cnt, dinv, b3, N);
    // FC + softmax (MFMA)
    fc_k<<<gb, 256, 0, stream>>>(Hh, fwh, FB, out, N);
}